// Round 4
// baseline (259.695 us; speedup 1.0000x reference)
//
#include <hip/hip_runtime.h>
#include <math.h>

#define H 512
#define B 2
#define S 256
#define BS 512
#define PI_F 3.14159265358979323846f
#define INV_SQRT_D 0.08838834764831845f  // 1/sqrt(128)

typedef __attribute__((ext_vector_type(8))) short short8;
typedef __attribute__((ext_vector_type(4))) float f32x4;
typedef __attribute__((ext_vector_type(4))) unsigned short ushort4v;

__device__ __forceinline__ unsigned short f2bf(float f) {
    unsigned u = __float_as_uint(f);
    u += 0x7FFFu + ((u >> 16) & 1u);      // round-to-nearest-even
    return (unsigned short)(u >> 16);
}

__device__ __forceinline__ void softmax3(const float* sw, float& w0, float& w1, float& w2)
{
    float s0 = sw[0], s1 = sw[1], s2 = sw[2];
    float mx = fmaxf(s0, fmaxf(s1, s2));
    float e0 = __expf(s0 - mx), e1 = __expf(s1 - mx), e2 = __expf(s2 - mx);
    float inv = 1.f / (e0 + e1 + e2);
    w0 = e0 * inv; w1 = e1 * inv; w2 = e2 * inv;
}

__device__ __forceinline__ void gload16(const unsigned short* g, void* l) {
    __builtin_amdgcn_global_load_lds(
        (const __attribute__((address_space(1))) unsigned int*)g,
        (__attribute__((address_space(3))) unsigned int*)l,
        16, 0, 0);
}

// ------------------------------------------------------------------
// Shared MFMA GEMM body. Ablk/Btblk are pre-offset to the block's
// row0/col0 (row0/col0 params used only for the C epilogue).
// 64x64 tile, BK=64, 4 waves (2x2), double-buffered LDS, 2-phase
// prefetch (stage next tile before MFMA on current; one barrier/step).
// XOR-swizzled LDS both-sides (pre-swizzled global src + swizzled read).
// EPI: 1 = fp32 out + qkvt col-activation + bias
//      3 = fp32 partial out, no bias
//      4 = bf16 out, no bias
// ------------------------------------------------------------------
template<int EPI>
__device__ __forceinline__ void gemm_body(
    const unsigned short* __restrict__ Ablk, int lda,
    const unsigned short* __restrict__ Btblk, int ldb,
    const float* __restrict__ bias,
    void* __restrict__ Cout, int ldc,
    int row0, int col0, int nk,
    unsigned short (*As)[4096], unsigned short (*Bs)[4096])
{
    const int tid = threadIdx.x;
    const int lane = tid & 63, wave = tid >> 6;
    const int wr = wave >> 1, wc = wave & 1;
    const int rowA = tid >> 3;                               // 0..31
    const int sb = ((tid & 7) << 4) ^ ((rowA & 7) << 4);     // swizzled byte-in-row
    const size_t offA0 = (size_t)rowA * lda + (sb >> 1);
    const size_t offA1 = offA0 + (size_t)32 * lda;
    const size_t offB0 = (size_t)rowA * ldb + (sb >> 1);
    const size_t offB1 = offB0 + (size_t)32 * ldb;
    const unsigned ldsO0 = wave * 1024u, ldsO1 = ldsO0 + 4096u;

    const int fr = lane & 15, grp = lane >> 4;
    int aA[2][2], aB[2][2];
    #pragma unroll
    for (int kk = 0; kk < 2; ++kk)
        #pragma unroll
        for (int f = 0; f < 2; ++f) {
            int ra = wr * 32 + f * 16 + fr;
            int rb = wc * 32 + f * 16 + fr;
            aA[f][kk] = (ra * 128 + kk * 64 + grp * 16) ^ ((ra & 7) << 4);
            aB[f][kk] = (rb * 128 + kk * 64 + grp * 16) ^ ((rb & 7) << 4);
        }

    auto stage = [&](int buf, int k0) {
        char* ab = (char*)As[buf]; char* bb = (char*)Bs[buf];
        gload16(Ablk  + offA0 + k0, ab + ldsO0);
        gload16(Ablk  + offA1 + k0, ab + ldsO1);
        gload16(Btblk + offB0 + k0, bb + ldsO0);
        gload16(Btblk + offB1 + k0, bb + ldsO1);
    };

    stage(0, 0);
    __syncthreads();
    f32x4 acc[2][2] = {};
    int cur = 0;
    for (int t = 0; t < nk; ++t) {
        if (t + 1 < nk) stage(cur ^ 1, (t + 1) * 64);
        const char* AsB = (const char*)As[cur];
        const char* BsB = (const char*)Bs[cur];
        #pragma unroll
        for (int kk = 0; kk < 2; ++kk) {
            short8 a0 = *(const short8*)(AsB + aA[0][kk]);
            short8 a1 = *(const short8*)(AsB + aA[1][kk]);
            short8 b0 = *(const short8*)(BsB + aB[0][kk]);
            short8 b1 = *(const short8*)(BsB + aB[1][kk]);
            acc[0][0] = __builtin_amdgcn_mfma_f32_16x16x32_bf16(a0, b0, acc[0][0], 0, 0, 0);
            acc[0][1] = __builtin_amdgcn_mfma_f32_16x16x32_bf16(a0, b1, acc[0][1], 0, 0, 0);
            acc[1][0] = __builtin_amdgcn_mfma_f32_16x16x32_bf16(a1, b0, acc[1][0], 0, 0, 0);
            acc[1][1] = __builtin_amdgcn_mfma_f32_16x16x32_bf16(a1, b1, acc[1][1], 0, 0, 0);
        }
        __syncthreads();
        cur ^= 1;
    }

    const int erow = row0 + wr * 32 + grp * 4;
    const int ecol = col0 + wc * 32 + fr;
    #pragma unroll
    for (int fm = 0; fm < 2; ++fm)
        #pragma unroll
        for (int fn = 0; fn < 2; ++fn)
            #pragma unroll
            for (int j = 0; j < 4; ++j) {
                int r = erow + fm * 16 + j;
                int c = ecol + fn * 16;
                float v = acc[fm][fn][j];
                if (EPI == 1) {
                    v += bias[c];
                    if (c < 512)       v = PI_F / (1.f + __expf(-v));
                    else if (c < 1024) v = 1.f  / (1.f + __expf(-v));
                }
                if (EPI == 4) ((unsigned short*)Cout)[(size_t)r * ldc + c] = f2bf(v);
                else          ((float*)Cout)[(size_t)r * ldc + c] = v;
            }
}

// ------------------------------------------------------------------
// Conv-as-GEMM body, split-K=4; A read from zero-padded xpad[B][264][512]
// (xpad row = s + tap; k = tap*512 + i). fp32 partials to convP[z].
// ------------------------------------------------------------------
__device__ __forceinline__ void conv_body(
    const unsigned short* __restrict__ xpad,
    const unsigned short* __restrict__ WbigT,
    float* __restrict__ convP, int bm, int bn, int z,
    unsigned short (*As)[4096], unsigned short (*Bs)[4096])
{
    const int tid = threadIdx.x;
    const int lane = tid & 63, wave = tid >> 6;
    const int wr = wave >> 1, wc = wave & 1;
    const int rowA = tid >> 3;
    const int sb = ((tid & 7) << 4) ^ ((rowA & 7) << 4);
    const int sbk = sb >> 1;
    const int r0 = bm * 64 + rowA;
    const int base0 = ((r0 >> 8) * 264 + (r0 & 255)) * 512;
    const int r1 = r0 + 32;
    const int base1 = ((r1 >> 8) * 264 + (r1 & 255)) * 512;
    const size_t offB0 = (size_t)(bn * 64 + rowA) * 4608 + sbk;
    const size_t offB1 = offB0 + (size_t)32 * 4608;
    const unsigned ldsO0 = wave * 1024u, ldsO1 = ldsO0 + 4096u;
    const int kstart = z * 1152;

    const int fr = lane & 15, grp = lane >> 4;
    int aA[2][2], aB[2][2];
    #pragma unroll
    for (int kk = 0; kk < 2; ++kk)
        #pragma unroll
        for (int f = 0; f < 2; ++f) {
            int ra = wr * 32 + f * 16 + fr;
            int rb = wc * 32 + f * 16 + fr;
            aA[f][kk] = (ra * 128 + kk * 64 + grp * 16) ^ ((ra & 7) << 4);
            aB[f][kk] = (rb * 128 + kk * 64 + grp * 16) ^ ((rb & 7) << 4);
        }

    auto stage = [&](int buf, int k0) {
        int tap = k0 >> 9;
        int ro = tap * 512 + (k0 & 511) + sbk;
        char* ab = (char*)As[buf]; char* bb = (char*)Bs[buf];
        gload16(xpad + base0 + ro, ab + ldsO0);
        gload16(xpad + base1 + ro, ab + ldsO1);
        gload16(WbigT + offB0 + k0, bb + ldsO0);
        gload16(WbigT + offB1 + k0, bb + ldsO1);
    };

    stage(0, kstart);
    __syncthreads();
    f32x4 acc[2][2] = {};
    int cur = 0;
    for (int t = 0; t < 18; ++t) {
        if (t < 17) stage(cur ^ 1, kstart + (t + 1) * 64);
        const char* AsB = (const char*)As[cur];
        const char* BsB = (const char*)Bs[cur];
        #pragma unroll
        for (int kk = 0; kk < 2; ++kk) {
            short8 a0 = *(const short8*)(AsB + aA[0][kk]);
            short8 a1 = *(const short8*)(AsB + aA[1][kk]);
            short8 b0 = *(const short8*)(BsB + aB[0][kk]);
            short8 b1 = *(const short8*)(BsB + aB[1][kk]);
            acc[0][0] = __builtin_amdgcn_mfma_f32_16x16x32_bf16(a0, b0, acc[0][0], 0, 0, 0);
            acc[0][1] = __builtin_amdgcn_mfma_f32_16x16x32_bf16(a0, b1, acc[0][1], 0, 0, 0);
            acc[1][0] = __builtin_amdgcn_mfma_f32_16x16x32_bf16(a1, b0, acc[1][0], 0, 0, 0);
            acc[1][1] = __builtin_amdgcn_mfma_f32_16x16x32_bf16(a1, b1, acc[1][1], 0, 0, 0);
        }
        __syncthreads();
        cur ^= 1;
    }

    float* Cp = convP + (size_t)z * 262144;
    const int erow = bm * 64 + wr * 32 + grp * 4;
    const int ecol = bn * 64 + wc * 32 + fr;
    #pragma unroll
    for (int fm = 0; fm < 2; ++fm)
        #pragma unroll
        for (int fn = 0; fn < 2; ++fn)
            #pragma unroll
            for (int j = 0; j < 4; ++j)
                Cp[(size_t)(erow + fm * 16 + j) * 512 + ecol + fn * 16] = acc[fm][fn][j];
}

// ------------------------------------------------------------------
// Dispatch 1: all prep. Segments by blockIdx:
// [0,2304)      WbigT (combined conv weight), 4 elems/thread along i
// [2304,4352)   32x32-tile transposes: WcatT (1280), WprojT (768)
// [4352,4616)   xpad (zero-padded bf16 x), 4/thread
// [4616,5640)   flat bf16 converts: Wo_b | Wwl_b | Wfc_b, 4/thread
// [5640,5652)   bcat1 (qkv+tc biases) + beff (conv bias)
// [5652,5654)   bias_eff = bproj + [bo|bwl|bfc] @ Wproj
// ------------------------------------------------------------------
__global__ __launch_bounds__(256)
void prep_all(const float* __restrict__ x,
              const float* __restrict__ Wq, const float* __restrict__ Wk,
              const float* __restrict__ Wv, const float* __restrict__ Wtc,
              const float* __restrict__ Wo, const float* __restrict__ Wwl,
              const float* __restrict__ Wfc, const float* __restrict__ Wproj,
              const float* __restrict__ cw1, const float* __restrict__ cw2,
              const float* __restrict__ cw3, const float* __restrict__ scale_w,
              const float* __restrict__ bq, const float* __restrict__ bk,
              const float* __restrict__ bv, const float* __restrict__ btc,
              const float* __restrict__ cb1, const float* __restrict__ cb2,
              const float* __restrict__ cb3,
              const float* __restrict__ bo, const float* __restrict__ bwl,
              const float* __restrict__ bfc, const float* __restrict__ bproj,
              unsigned short* __restrict__ xpad, unsigned short* __restrict__ WcatT,
              unsigned short* __restrict__ WbigT, unsigned short* __restrict__ WprojT,
              unsigned short* __restrict__ Wo_b, unsigned short* __restrict__ Wwl_b,
              unsigned short* __restrict__ Wfc_b,
              float* __restrict__ bcat1, float* __restrict__ beff,
              float* __restrict__ bias_eff)
{
    int bid = blockIdx.x, tid = threadIdx.x;

    if (bid < 2304) {                       // WbigT [512 o][4608 = t*512+i]
        int g = bid * 256 + tid;            // < 589824
        int o = g / 1152, rem = g - o * 1152;
        int t = rem >> 7, i4 = (rem & 127) << 2;
        float w0, w1, w2; softmax3(scale_w, w0, w1, w2);
        ushort4v pk;
        #pragma unroll
        for (int q = 0; q < 4; ++q) {
            size_t oi = (size_t)o * 512 + i4 + q;
            float v = w2 * cw3[oi * 9 + t];
            if (t >= 3 && t < 6) v = fmaf(w0, cw1[oi * 3 + (t - 3)], v);
            if (t >= 2 && t < 7) v = fmaf(w1, cw2[oi * 5 + (t - 2)], v);
            pk[q] = f2bf(v);
        }
        *(ushort4v*)&WbigT[(size_t)o * 4608 + t * 512 + i4] = pk;
        return;
    }
    bid -= 2304;
    if (bid < 2048) {                       // transposes
        __shared__ float tile[32][33];
        int t = bid;
        const float* src; unsigned short* dst;
        int srcld, dstld, ntk, drow0;
        if (t < 256)       {            src = Wq;    srcld = 512;  dst = WcatT;  dstld = 512;  ntk = 16; drow0 = 0; }
        else if (t < 512)  { t -= 256;  src = Wk;    srcld = 512;  dst = WcatT;  dstld = 512;  ntk = 16; drow0 = 512; }
        else if (t < 768)  { t -= 512;  src = Wv;    srcld = 512;  dst = WcatT;  dstld = 512;  ntk = 16; drow0 = 1024; }
        else if (t < 1280) { t -= 768;  src = Wtc;   srcld = 1024; dst = WcatT;  dstld = 512;  ntk = 16; drow0 = 1536; }
        else               { t -= 1280; src = Wproj; srcld = 512;  dst = WprojT; dstld = 1536; ntk = 48; drow0 = 0; }
        int tk = t % ntk, tn = t / ntk;
        int r8 = tid >> 5, c = tid & 31;
        #pragma unroll
        for (int rr = 0; rr < 4; ++rr) {
            int r = r8 + rr * 8;
            tile[r][c] = src[(size_t)(tk * 32 + r) * srcld + tn * 32 + c];
        }
        __syncthreads();
        #pragma unroll
        for (int rr = 0; rr < 4; ++rr) {
            int r = r8 + rr * 8;
            dst[(size_t)(drow0 + tn * 32 + r) * dstld + tk * 32 + c] = f2bf(tile[c][r]);
        }
        return;
    }
    bid -= 2048;
    if (bid < 264) {                        // xpad[B][264][512]
        int e = bid * 1024 + tid * 4;       // < 270336
        int b = e / 135168, rem = e - b * 135168;
        int srow = rem >> 9, i4 = rem & 511;
        int s2 = srow - 4;
        ushort4v pk = {0, 0, 0, 0};
        if (s2 >= 0 && s2 < 256) {
            f32x4 v = *(const f32x4*)&x[((size_t)(b * 256 + s2) << 9) + i4];
            pk[0] = f2bf(v[0]); pk[1] = f2bf(v[1]); pk[2] = f2bf(v[2]); pk[3] = f2bf(v[3]);
        }
        *(ushort4v*)&xpad[e] = pk;
        return;
    }
    bid -= 264;
    if (bid < 1024) {                       // Wo_b | Wwl_b | Wfc_b flat converts
        int f = bid * 1024 + tid * 4;       // < 1048576
        const float* src; unsigned short* dst; int o;
        if (f < 262144)      { src = Wo;  dst = Wo_b;  o = f; }
        else if (f < 524288) { src = Wwl; dst = Wwl_b; o = f - 262144; }
        else                 { src = Wfc; dst = Wfc_b; o = f - 524288; }
        f32x4 v = *(const f32x4*)&src[o];
        ushort4v pk;
        pk[0] = f2bf(v[0]); pk[1] = f2bf(v[1]); pk[2] = f2bf(v[2]); pk[3] = f2bf(v[3]);
        *(ushort4v*)&dst[o] = pk;
        return;
    }
    bid -= 1024;
    if (bid < 12) {                         // bcat1 + beff
        int idx = bid * 256 + tid;
        if (idx < 2560) {
            float v;
            if (idx < 512)       v = bq[idx];
            else if (idx < 1024) v = bk[idx - 512];
            else if (idx < 1536) v = bv[idx - 1024];
            else                 v = btc[idx - 1536];
            bcat1[idx] = v;
        } else if (idx < 3072) {
            int c = idx - 2560;
            float w0, w1, w2; softmax3(scale_w, w0, w1, w2);
            beff[c] = w0 * cb1[c] + w1 * cb2[c] + w2 * cb3[c];
        }
        return;
    }
    bid -= 12;
    {                                       // bias_eff[512]
        int j = bid * 256 + tid;
        float acc = bproj[j];
        for (int k = 0; k < 1536; ++k) {
            float bk_ = (k < 512) ? bo[k] : (k < 1024) ? bwl[k - 512] : bfc[k - 1024];
            acc = fmaf(bk_, Wproj[(size_t)k * 512 + j], acc);
        }
        bias_eff[j] = acc;
    }
}

// ------------------------------------------------------------------
// Dispatch 2: all weight-side + input-side big GEMMs concurrently.
// [0,256)    conv split-K=4 partials
// [256,576)  qkvt = xpad @ WcatT (+bias, +sigmoid acts), fp32 [512][2560]
// [576,640)  WeffO_T  = (Wproj[0:512]^T) @ Wo^T   -> bf16 [512][512]
// [640,704)  WeffWl_T = (Wproj[512:1024]^T) @ Wwl^T -> bf16 [512][512]
// [704,832)  WeffFc_T = (Wproj[1024:1536]^T) @ Wfc^T -> bf16 [512][1024]
// ------------------------------------------------------------------
__global__ __launch_bounds__(256)
void big_gemms(const unsigned short* __restrict__ xpad,
               const unsigned short* __restrict__ WbigT, float* __restrict__ convP,
               const unsigned short* __restrict__ WcatT, const float* __restrict__ bcat1,
               float* __restrict__ qkvt,
               const unsigned short* __restrict__ WprojT,
               const unsigned short* __restrict__ Wo_b, const unsigned short* __restrict__ Wwl_b,
               const unsigned short* __restrict__ Wfc_b,
               unsigned short* __restrict__ WeffO_T, unsigned short* __restrict__ WeffWl_T,
               unsigned short* __restrict__ WeffFc_T)
{
    __shared__ unsigned short As[2][4096], Bs[2][4096];
    int bid = blockIdx.x;
    if (bid < 256) {
        conv_body(xpad, WbigT, convP, (bid >> 3) & 7, bid & 7, bid >> 6, As, Bs);
        return;
    }
    bid -= 256;
    if (bid < 320) {
        int bm = bid / 40, bn = bid % 40;
        int r0 = bm * 64;
        const unsigned short* Axp = xpad + ((size_t)(r0 >> 8) * 264 + (r0 & 255) + 4) * 512;
        gemm_body<1>(Axp, 512, WcatT + (size_t)bn * 64 * 512, 512, bcat1,
                     qkvt, 2560, r0, bn * 64, 8, As, Bs);
        return;
    }
    bid -= 320;
    if (bid < 64) {
        int bm = bid >> 3, bn = bid & 7;
        gemm_body<4>(WprojT + (size_t)bm * 64 * 1536, 1536, Wo_b + (size_t)bn * 64 * 512, 512,
                     nullptr, WeffO_T, 512, bm * 64, bn * 64, 8, As, Bs);
        return;
    }
    bid -= 64;
    if (bid < 64) {
        int bm = bid >> 3, bn = bid & 7;
        gemm_body<4>(WprojT + 512 + (size_t)bm * 64 * 1536, 1536, Wwl_b + (size_t)bn * 64 * 512, 512,
                     nullptr, WeffWl_T, 512, bm * 64, bn * 64, 8, As, Bs);
        return;
    }
    bid -= 64;
    {   // WeffFc_T: M=512, N=1024, K=512
        int bm = bid >> 4, bn = bid & 15;
        gemm_body<4>(WprojT + 1024 + (size_t)bm * 64 * 1536, 1536, Wfc_b + (size_t)bn * 64 * 512, 512,
                     nullptr, WeffFc_T, 1024, bm * 64, bn * 64, 8, As, Bs);
    }
}

// ------------------------------------------------------------------
// Dispatch 3: branch nonlinears.
// [0,1024)     attn: block = (bi, half), 256 thr = 256 channels
// [1024,2048)  phase: block = (b,c), 256 thr = S
// [2048,3072)  conv split-K reduce -> bf16 convout
// ------------------------------------------------------------------
__global__ __launch_bounds__(256)
void branches(const float* __restrict__ qkvt, const float* __restrict__ phase_shifts,
              const float* __restrict__ convP, const float* __restrict__ beff,
              unsigned short* __restrict__ ctx_b, unsigned short* __restrict__ nc_b,
              unsigned short* __restrict__ convout)
{
    int bid = blockIdx.x, tid = threadIdx.x;
    if (bid < 1024) {                       // wave attention
        const int bi = bid >> 1;
        const int b = bi >> 8, i = bi & 255;
        const int c = ((bid & 1) << 8) + tid;
        const float* qrow = qkvt + (size_t)bi * 2560;
        const float om = qrow[c];
        const float am = qrow[512 + c] * INV_SQRT_D;
        const float ph = tanhf(qrow[1024 + c]) * PI_F;
        const float* vb = qkvt + (size_t)(b * 256) * 2560 + 1024 + c;
        float se = 0.f, sev = 0.f;
        for (int j = 0; j < 256; ++j) {
            float ang = fmaf(om, (float)(i - j), ph);
            float e = __expf(am * __cosf(ang));
            se += e;
            sev = fmaf(e, vb[(size_t)j * 2560], sev);
        }
        ctx_b[(size_t)bi * 512 + c] = f2bf(sev / se);
        return;
    }
    bid -= 1024;
    if (bid < 1024) {                       // phase branch
        const int b = bid >> 9, c = bid & 511;
        const int s = tid;
        const float* row = qkvt + (size_t)(b * 256 + s) * 2560 + 1536;
        float re = row[c], im = row[c + 512];
        float p = atan2f(im, re);
        float mag = sqrtf(fmaf(re, re, fmaf(im, im, 1e-5f)));
        float sp, cp; sincosf(p, &sp, &cp);
        float cs = cp, sn = sp;
        #pragma unroll
        for (int m = 32; m; m >>= 1) { cs += __shfl_xor(cs, m); sn += __shfl_xor(sn, m); }
        __shared__ float wred[8];
        int w = s >> 6, l = s & 63;
        if (l == 0) { wred[w] = cs; wred[4 + w] = sn; }
        __syncthreads();
        float mcv = (wred[0] + wred[1] + wred[2] + wred[3]) * (1.f / 256.f);
        float msv = (wred[4] + wred[5] + wred[6] + wred[7]) * (1.f / 256.f);
        float psh = phase_shifts[c];
        float s2_, c2_; sincosf(p + psh, &s2_, &c2_);
        float mixed = c2_ * mcv + s2_ * msv;
        float np_ = fmaf(0.1f, mixed, p);
        float snn, cnn; sincosf(np_, &snn, &cnn);
        size_t o = (size_t)(b * 256 + s) * 1024 + c;
        nc_b[o]       = f2bf(mag * cnn);
        nc_b[o + 512] = f2bf(mag * snn);
        return;
    }
    bid -= 1024;
    {                                       // conv reduce
        int idx = bid * 256 + tid;
        int c = idx & 511;
        float v = beff[c] + convP[idx] + convP[idx + 262144] + convP[idx + 524288] + convP[idx + 786432];
        convout[idx] = f2bf(v);
    }
}

// ------------------------------------------------------------------
// Dispatch 4: branch-output GEMMs against pre-multiplied weights,
// fp32 partials P[z] (z = 0:ctx@WeffO, 1:conv@WeffWl, 2:nc@WeffFc).
// ------------------------------------------------------------------
__global__ __launch_bounds__(256)
void mid_gemms(const unsigned short* __restrict__ ctx_b, const unsigned short* __restrict__ convout,
               const unsigned short* __restrict__ nc_b,
               const unsigned short* __restrict__ WeffO_T, const unsigned short* __restrict__ WeffWl_T,
               const unsigned short* __restrict__ WeffFc_T,
               float* __restrict__ P)
{
    __shared__ unsigned short As[2][4096], Bs[2][4096];
    int bid = blockIdx.x;
    int z = bid >> 6, bm = (bid >> 3) & 7, bn = bid & 7;
    if (z == 0)
        gemm_body<3>(ctx_b + (size_t)bm * 64 * 512, 512, WeffO_T + (size_t)bn * 64 * 512, 512,
                     nullptr, P, 512, bm * 64, bn * 64, 8, As, Bs);
    else if (z == 1)
        gemm_body<3>(convout + (size_t)bm * 64 * 512, 512, WeffWl_T + (size_t)bn * 64 * 512, 512,
                     nullptr, P + 262144, 512, bm * 64, bn * 64, 8, As, Bs);
    else
        gemm_body<3>(nc_b + (size_t)bm * 64 * 1024, 1024, WeffFc_T + (size_t)bn * 64 * 1024, 1024,
                     nullptr, P + 524288, 512, bm * 64, bn * 64, 16, As, Bs);
}

// ------------------------------------------------------------------
// Dispatch 5: sum partials + bias_eff + residual + LayerNorm -> out
// ------------------------------------------------------------------
__global__ __launch_bounds__(256)
void final_ln(const float* __restrict__ x, const float* __restrict__ P,
              const float* __restrict__ bias_eff,
              const float* __restrict__ g, const float* __restrict__ bta,
              float* __restrict__ out)
{
    int r = blockIdx.x, t = threadIdx.x;
    size_t o0 = (size_t)r * 512 + t, o1 = o0 + 256;
    float c0 = bias_eff[t]       + P[o0] + P[o0 + 262144] + P[o0 + 524288];
    float c1 = bias_eff[t + 256] + P[o1] + P[o1 + 262144] + P[o1 + 524288];
    float v0 = x[o0] + c0, v1 = x[o1] + c1;
    float sum = v0 + v1;
    #pragma unroll
    for (int m = 32; m; m >>= 1) sum += __shfl_xor(sum, m);
    __shared__ float wred[8];
    int w = t >> 6, l = t & 63;
    if (l == 0) wred[w] = sum;
    __syncthreads();
    float mu = (wred[0] + wred[1] + wred[2] + wred[3]) * (1.f / 512.f);
    float d0 = v0 - mu, d1 = v1 - mu;
    float s2 = d0 * d0 + d1 * d1;
    #pragma unroll
    for (int m = 32; m; m >>= 1) s2 += __shfl_xor(s2, m);
    if (l == 0) wred[4 + w] = s2;
    __syncthreads();
    float inv = rsqrtf((wred[4] + wred[5] + wred[6] + wred[7]) * (1.f / 512.f) + 1e-5f);
    out[o0] = d0 * inv * g[t]       + bta[t];
    out[o1] = d1 * inv * g[t + 256] + bta[t + 256];
}

// ------------------------------------------------------------------
extern "C" void kernel_launch(void* const* d_in, const int* in_sizes, int n_in,
                              void* d_out, int out_size, void* d_ws, size_t ws_size,
                              hipStream_t stream)
{
    const float* x   = (const float*)d_in[0];
    const float* Wq  = (const float*)d_in[1];
    const float* bq  = (const float*)d_in[2];
    const float* Wk  = (const float*)d_in[3];
    const float* bk  = (const float*)d_in[4];
    const float* Wv  = (const float*)d_in[5];
    const float* bv  = (const float*)d_in[6];
    const float* Wo  = (const float*)d_in[7];
    const float* bo  = (const float*)d_in[8];
    const float* cw1 = (const float*)d_in[9];
    const float* cb1 = (const float*)d_in[10];
    const float* cw2 = (const float*)d_in[11];
    const float* cb2 = (const float*)d_in[12];
    const float* cw3 = (const float*)d_in[13];
    const float* cb3 = (const float*)d_in[14];
    const float* scale_w = (const float*)d_in[15];
    const float* Wwl = (const float*)d_in[16];
    const float* bwl = (const float*)d_in[17];
    const float* Wtc = (const float*)d_in[18];
    const float* btc = (const float*)d_in[19];
    const float* Wfc = (const float*)d_in[20];
    const float* bfc = (const float*)d_in[21];
    const float* phase_shifts = (const float*)d_in[22];
    const float* Wproj = (const float*)d_in[23];
    const float* bproj = (const float*)d_in[24];
    const float* ln_g = (const float*)d_in[25];
    const float* ln_b = (const float*)d_in[26];
    float* out = (float*)d_out;

    // ---- workspace layout ----
    float* wsf      = (float*)d_ws;
    float* qkvt     = wsf;                      // 1,310,720 f
    float* convP    = qkvt + 1310720;           // 1,048,576 f (4 x 512x512)
    float* P        = convP + 1048576;          //   786,432 f (3 x 512x512)
    float* bcat1    = P + 786432;               //     2,560 f
    float* beff     = bcat1 + 2560;             //       512 f
    float* bias_eff = beff + 512;               //       512 f
    unsigned short* u = (unsigned short*)(bias_eff + 512);
    unsigned short* xpad     = u;                    // 270,336
    unsigned short* WcatT    = xpad + 270336;        // 1,310,720
    unsigned short* WbigT    = WcatT + 1310720;      // 2,359,296
    unsigned short* WprojT   = WbigT + 2359296;      // 786,432
    unsigned short* Wo_b     = WprojT + 786432;      // 262,144
    unsigned short* Wwl_b    = Wo_b + 262144;        // 262,144
    unsigned short* Wfc_b    = Wwl_b + 262144;       // 524,288
    unsigned short* WeffO_T  = Wfc_b + 524288;       // 262,144
    unsigned short* WeffWl_T = WeffO_T + 262144;     // 262,144
    unsigned short* WeffFc_T = WeffWl_T + 262144;    // 524,288
    unsigned short* convout  = WeffFc_T + 524288;    // 262,144
    unsigned short* ctx_b    = convout + 262144;     // 262,144
    unsigned short* nc_b     = ctx_b + 262144;       // 524,288

    prep_all<<<5654, 256, 0, stream>>>(x, Wq, Wk, Wv, Wtc, Wo, Wwl, Wfc, Wproj,
                                       cw1, cw2, cw3, scale_w,
                                       bq, bk, bv, btc, cb1, cb2, cb3,
                                       bo, bwl, bfc, bproj,
                                       xpad, WcatT, WbigT, WprojT,
                                       Wo_b, Wwl_b, Wfc_b,
                                       bcat1, beff, bias_eff);

    big_gemms<<<832, 256, 0, stream>>>(xpad, WbigT, convP, WcatT, bcat1, qkvt,
                                       WprojT, Wo_b, Wwl_b, Wfc_b,
                                       WeffO_T, WeffWl_T, WeffFc_T);

    branches<<<3072, 256, 0, stream>>>(qkvt, phase_shifts, convP, beff,
                                       ctx_b, nc_b, convout);

    mid_gemms<<<192, 256, 0, stream>>>(ctx_b, convout, nc_b,
                                       WeffO_T, WeffWl_T, WeffFc_T, P);

    final_ln<<<512, 256, 0, stream>>>(x, P, bias_eff, ln_g, ln_b, out);
}

// Round 5
// 108.030 us; speedup vs baseline: 2.4039x; 2.4039x over previous
//
#include <hip/hip_runtime.h>
#include <math.h>

#define H 512
#define B 2
#define S 256
#define BS 512
#define PI_F 3.14159265358979323846f
#define INV_SQRT_D 0.08838834764831845f  // 1/sqrt(128)

typedef __attribute__((ext_vector_type(8))) short short8;
typedef __attribute__((ext_vector_type(4))) float f32x4;
typedef __attribute__((ext_vector_type(4))) unsigned short ushort4v;

__device__ __forceinline__ unsigned short f2bf(float f) {
    unsigned u = __float_as_uint(f);
    u += 0x7FFFu + ((u >> 16) & 1u);      // round-to-nearest-even
    return (unsigned short)(u >> 16);
}

__device__ __forceinline__ void softmax3(const float* sw, float& w0, float& w1, float& w2)
{
    float s0 = sw[0], s1 = sw[1], s2 = sw[2];
    float mx = fmaxf(s0, fmaxf(s1, s2));
    float e0 = __expf(s0 - mx), e1 = __expf(s1 - mx), e2 = __expf(s2 - mx);
    float inv = 1.f / (e0 + e1 + e2);
    w0 = e0 * inv; w1 = e1 * inv; w2 = e2 * inv;
}

__device__ __forceinline__ void gload16(const unsigned short* g, void* l) {
    __builtin_amdgcn_global_load_lds(
        (const __attribute__((address_space(1))) unsigned int*)g,
        (__attribute__((address_space(3))) unsigned int*)l,
        16, 0, 0);
}

// ------------------------------------------------------------------
// Shared MFMA GEMM body (64x64 tile, BK=64, 4 waves, dbuf LDS,
// 2-phase prefetch, XOR-swizzled LDS both-sides).
// EPI: 1 = fp32 out + qkvt col-activation + bias
//      3 = fp32 partial out, no bias
//      4 = bf16 out, no bias
// ------------------------------------------------------------------
template<int EPI>
__device__ __forceinline__ void gemm_body(
    const unsigned short* __restrict__ Ablk, int lda,
    const unsigned short* __restrict__ Btblk, int ldb,
    const float* __restrict__ bias,
    void* __restrict__ Cout, int ldc,
    int row0, int col0, int nk,
    unsigned short (*As)[4096], unsigned short (*Bs)[4096])
{
    const int tid = threadIdx.x;
    const int lane = tid & 63, wave = tid >> 6;
    const int wr = wave >> 1, wc = wave & 1;
    const int rowA = tid >> 3;                               // 0..31
    const int sb = ((tid & 7) << 4) ^ ((rowA & 7) << 4);     // swizzled byte-in-row
    const size_t offA0 = (size_t)rowA * lda + (sb >> 1);
    const size_t offA1 = offA0 + (size_t)32 * lda;
    const size_t offB0 = (size_t)rowA * ldb + (sb >> 1);
    const size_t offB1 = offB0 + (size_t)32 * ldb;
    const unsigned ldsO0 = wave * 1024u, ldsO1 = ldsO0 + 4096u;

    const int fr = lane & 15, grp = lane >> 4;
    int aA[2][2], aB[2][2];
    #pragma unroll
    for (int kk = 0; kk < 2; ++kk)
        #pragma unroll
        for (int f = 0; f < 2; ++f) {
            int ra = wr * 32 + f * 16 + fr;
            int rb = wc * 32 + f * 16 + fr;
            aA[f][kk] = (ra * 128 + kk * 64 + grp * 16) ^ ((ra & 7) << 4);
            aB[f][kk] = (rb * 128 + kk * 64 + grp * 16) ^ ((rb & 7) << 4);
        }

    auto stage = [&](int buf, int k0) {
        char* ab = (char*)As[buf]; char* bb = (char*)Bs[buf];
        gload16(Ablk  + offA0 + k0, ab + ldsO0);
        gload16(Ablk  + offA1 + k0, ab + ldsO1);
        gload16(Btblk + offB0 + k0, bb + ldsO0);
        gload16(Btblk + offB1 + k0, bb + ldsO1);
    };

    stage(0, 0);
    __syncthreads();
    f32x4 acc[2][2] = {};
    int cur = 0;
    for (int t = 0; t < nk; ++t) {
        if (t + 1 < nk) stage(cur ^ 1, (t + 1) * 64);
        const char* AsB = (const char*)As[cur];
        const char* BsB = (const char*)Bs[cur];
        #pragma unroll
        for (int kk = 0; kk < 2; ++kk) {
            short8 a0 = *(const short8*)(AsB + aA[0][kk]);
            short8 a1 = *(const short8*)(AsB + aA[1][kk]);
            short8 b0 = *(const short8*)(BsB + aB[0][kk]);
            short8 b1 = *(const short8*)(BsB + aB[1][kk]);
            acc[0][0] = __builtin_amdgcn_mfma_f32_16x16x32_bf16(a0, b0, acc[0][0], 0, 0, 0);
            acc[0][1] = __builtin_amdgcn_mfma_f32_16x16x32_bf16(a0, b1, acc[0][1], 0, 0, 0);
            acc[1][0] = __builtin_amdgcn_mfma_f32_16x16x32_bf16(a1, b0, acc[1][0], 0, 0, 0);
            acc[1][1] = __builtin_amdgcn_mfma_f32_16x16x32_bf16(a1, b1, acc[1][1], 0, 0, 0);
        }
        __syncthreads();
        cur ^= 1;
    }

    const int erow = row0 + wr * 32 + grp * 4;
    const int ecol = col0 + wc * 32 + fr;
    #pragma unroll
    for (int fm = 0; fm < 2; ++fm)
        #pragma unroll
        for (int fn = 0; fn < 2; ++fn)
            #pragma unroll
            for (int j = 0; j < 4; ++j) {
                int r = erow + fm * 16 + j;
                int c = ecol + fn * 16;
                float v = acc[fm][fn][j];
                if (EPI == 1) {
                    v += bias[c];
                    if (c < 512)       v = PI_F / (1.f + __expf(-v));
                    else if (c < 1024) v = 1.f  / (1.f + __expf(-v));
                }
                if (EPI == 4) ((unsigned short*)Cout)[(size_t)r * ldc + c] = f2bf(v);
                else          ((float*)Cout)[(size_t)r * ldc + c] = v;
            }
}

// ------------------------------------------------------------------
// Conv-as-GEMM body, split-K=4; A read from zero-padded xpad[B][264][512]
// (xpad row = s + tap; k = tap*512 + i). fp32 partials to convP[z].
// ------------------------------------------------------------------
__device__ __forceinline__ void conv_body(
    const unsigned short* __restrict__ xpad,
    const unsigned short* __restrict__ WbigT,
    float* __restrict__ convP, int bm, int bn, int z,
    unsigned short (*As)[4096], unsigned short (*Bs)[4096])
{
    const int tid = threadIdx.x;
    const int lane = tid & 63, wave = tid >> 6;
    const int wr = wave >> 1, wc = wave & 1;
    const int rowA = tid >> 3;
    const int sb = ((tid & 7) << 4) ^ ((rowA & 7) << 4);
    const int sbk = sb >> 1;
    const int r0 = bm * 64 + rowA;
    const int base0 = ((r0 >> 8) * 264 + (r0 & 255)) * 512;
    const int r1 = r0 + 32;
    const int base1 = ((r1 >> 8) * 264 + (r1 & 255)) * 512;
    const size_t offB0 = (size_t)(bn * 64 + rowA) * 4608 + sbk;
    const size_t offB1 = offB0 + (size_t)32 * 4608;
    const unsigned ldsO0 = wave * 1024u, ldsO1 = ldsO0 + 4096u;
    const int kstart = z * 1152;

    const int fr = lane & 15, grp = lane >> 4;
    int aA[2][2], aB[2][2];
    #pragma unroll
    for (int kk = 0; kk < 2; ++kk)
        #pragma unroll
        for (int f = 0; f < 2; ++f) {
            int ra = wr * 32 + f * 16 + fr;
            int rb = wc * 32 + f * 16 + fr;
            aA[f][kk] = (ra * 128 + kk * 64 + grp * 16) ^ ((ra & 7) << 4);
            aB[f][kk] = (rb * 128 + kk * 64 + grp * 16) ^ ((rb & 7) << 4);
        }

    auto stage = [&](int buf, int k0) {
        int tap = k0 >> 9;
        int ro = tap * 512 + (k0 & 511) + sbk;
        char* ab = (char*)As[buf]; char* bb = (char*)Bs[buf];
        gload16(xpad + base0 + ro, ab + ldsO0);
        gload16(xpad + base1 + ro, ab + ldsO1);
        gload16(WbigT + offB0 + k0, bb + ldsO0);
        gload16(WbigT + offB1 + k0, bb + ldsO1);
    };

    stage(0, kstart);
    __syncthreads();
    f32x4 acc[2][2] = {};
    int cur = 0;
    for (int t = 0; t < 18; ++t) {
        if (t < 17) stage(cur ^ 1, kstart + (t + 1) * 64);
        const char* AsB = (const char*)As[cur];
        const char* BsB = (const char*)Bs[cur];
        #pragma unroll
        for (int kk = 0; kk < 2; ++kk) {
            short8 a0 = *(const short8*)(AsB + aA[0][kk]);
            short8 a1 = *(const short8*)(AsB + aA[1][kk]);
            short8 b0 = *(const short8*)(BsB + aB[0][kk]);
            short8 b1 = *(const short8*)(BsB + aB[1][kk]);
            acc[0][0] = __builtin_amdgcn_mfma_f32_16x16x32_bf16(a0, b0, acc[0][0], 0, 0, 0);
            acc[0][1] = __builtin_amdgcn_mfma_f32_16x16x32_bf16(a0, b1, acc[0][1], 0, 0, 0);
            acc[1][0] = __builtin_amdgcn_mfma_f32_16x16x32_bf16(a1, b0, acc[1][0], 0, 0, 0);
            acc[1][1] = __builtin_amdgcn_mfma_f32_16x16x32_bf16(a1, b1, acc[1][1], 0, 0, 0);
        }
        __syncthreads();
        cur ^= 1;
    }

    float* Cp = convP + (size_t)z * 262144;
    const int erow = bm * 64 + wr * 32 + grp * 4;
    const int ecol = bn * 64 + wc * 32 + fr;
    #pragma unroll
    for (int fm = 0; fm < 2; ++fm)
        #pragma unroll
        for (int fn = 0; fn < 2; ++fn)
            #pragma unroll
            for (int j = 0; j < 4; ++j)
                Cp[(size_t)(erow + fm * 16 + j) * 512 + ecol + fn * 16] = acc[fm][fn][j];
}

// ------------------------------------------------------------------
// Dispatch 1: all prep. Segments by blockIdx:
// [0,2304)      WbigT (combined conv weight), 4 elems/thread along i
// [2304,4352)   32x32-tile transposes: WcatT (1280), WprojT (768)
// [4352,4616)   xpad (zero-padded bf16 x), 4/thread
// [4616,5640)   flat bf16 converts: Wo_b | Wwl_b | Wfc_b, 4/thread
// [5640,5652)   bcat1 (qkv+tc biases) + beff (conv bias)
// [5652,6164)   bias_eff[j] = bproj[j] + [bo|bwl|bfc] @ Wproj[:,j]
//               (one block per j, 256 thr x 6 k, parallel reduce —
//                round-4's 2-block serial loop was a 200 us tail)
// ------------------------------------------------------------------
__global__ __launch_bounds__(256)
void prep_all(const float* __restrict__ x,
              const float* __restrict__ Wq, const float* __restrict__ Wk,
              const float* __restrict__ Wv, const float* __restrict__ Wtc,
              const float* __restrict__ Wo, const float* __restrict__ Wwl,
              const float* __restrict__ Wfc, const float* __restrict__ Wproj,
              const float* __restrict__ cw1, const float* __restrict__ cw2,
              const float* __restrict__ cw3, const float* __restrict__ scale_w,
              const float* __restrict__ bq, const float* __restrict__ bk,
              const float* __restrict__ bv, const float* __restrict__ btc,
              const float* __restrict__ cb1, const float* __restrict__ cb2,
              const float* __restrict__ cb3,
              const float* __restrict__ bo, const float* __restrict__ bwl,
              const float* __restrict__ bfc, const float* __restrict__ bproj,
              unsigned short* __restrict__ xpad, unsigned short* __restrict__ WcatT,
              unsigned short* __restrict__ WbigT, unsigned short* __restrict__ WprojT,
              unsigned short* __restrict__ Wo_b, unsigned short* __restrict__ Wwl_b,
              unsigned short* __restrict__ Wfc_b,
              float* __restrict__ bcat1, float* __restrict__ beff,
              float* __restrict__ bias_eff)
{
    int bid = blockIdx.x, tid = threadIdx.x;

    if (bid < 2304) {                       // WbigT [512 o][4608 = t*512+i]
        int g = bid * 256 + tid;            // < 589824
        int o = g / 1152, rem = g - o * 1152;
        int t = rem >> 7, i4 = (rem & 127) << 2;
        float w0, w1, w2; softmax3(scale_w, w0, w1, w2);
        ushort4v pk;
        #pragma unroll
        for (int q = 0; q < 4; ++q) {
            size_t oi = (size_t)o * 512 + i4 + q;
            float v = w2 * cw3[oi * 9 + t];
            if (t >= 3 && t < 6) v = fmaf(w0, cw1[oi * 3 + (t - 3)], v);
            if (t >= 2 && t < 7) v = fmaf(w1, cw2[oi * 5 + (t - 2)], v);
            pk[q] = f2bf(v);
        }
        *(ushort4v*)&WbigT[(size_t)o * 4608 + t * 512 + i4] = pk;
        return;
    }
    bid -= 2304;
    if (bid < 2048) {                       // transposes
        __shared__ float tile[32][33];
        int t = bid;
        const float* src; unsigned short* dst;
        int srcld, dstld, ntk, drow0;
        if (t < 256)       {            src = Wq;    srcld = 512;  dst = WcatT;  dstld = 512;  ntk = 16; drow0 = 0; }
        else if (t < 512)  { t -= 256;  src = Wk;    srcld = 512;  dst = WcatT;  dstld = 512;  ntk = 16; drow0 = 512; }
        else if (t < 768)  { t -= 512;  src = Wv;    srcld = 512;  dst = WcatT;  dstld = 512;  ntk = 16; drow0 = 1024; }
        else if (t < 1280) { t -= 768;  src = Wtc;   srcld = 1024; dst = WcatT;  dstld = 512;  ntk = 16; drow0 = 1536; }
        else               { t -= 1280; src = Wproj; srcld = 512;  dst = WprojT; dstld = 1536; ntk = 48; drow0 = 0; }
        int tk = t % ntk, tn = t / ntk;
        int r8 = tid >> 5, c = tid & 31;
        #pragma unroll
        for (int rr = 0; rr < 4; ++rr) {
            int r = r8 + rr * 8;
            tile[r][c] = src[(size_t)(tk * 32 + r) * srcld + tn * 32 + c];
        }
        __syncthreads();
        #pragma unroll
        for (int rr = 0; rr < 4; ++rr) {
            int r = r8 + rr * 8;
            dst[(size_t)(drow0 + tn * 32 + r) * dstld + tk * 32 + c] = f2bf(tile[c][r]);
        }
        return;
    }
    bid -= 2048;
    if (bid < 264) {                        // xpad[B][264][512]
        int e = bid * 1024 + tid * 4;       // < 270336
        int b = e / 135168, rem = e - b * 135168;
        int srow = rem >> 9, i4 = rem & 511;
        int s2 = srow - 4;
        ushort4v pk = {0, 0, 0, 0};
        if (s2 >= 0 && s2 < 256) {
            f32x4 v = *(const f32x4*)&x[((size_t)(b * 256 + s2) << 9) + i4];
            pk[0] = f2bf(v[0]); pk[1] = f2bf(v[1]); pk[2] = f2bf(v[2]); pk[3] = f2bf(v[3]);
        }
        *(ushort4v*)&xpad[e] = pk;
        return;
    }
    bid -= 264;
    if (bid < 1024) {                       // Wo_b | Wwl_b | Wfc_b flat converts
        int f = bid * 1024 + tid * 4;       // < 1048576
        const float* src; unsigned short* dst; int o;
        if (f < 262144)      { src = Wo;  dst = Wo_b;  o = f; }
        else if (f < 524288) { src = Wwl; dst = Wwl_b; o = f - 262144; }
        else                 { src = Wfc; dst = Wfc_b; o = f - 524288; }
        f32x4 v = *(const f32x4*)&src[o];
        ushort4v pk;
        pk[0] = f2bf(v[0]); pk[1] = f2bf(v[1]); pk[2] = f2bf(v[2]); pk[3] = f2bf(v[3]);
        *(ushort4v*)&dst[o] = pk;
        return;
    }
    bid -= 1024;
    if (bid < 12) {                         // bcat1 + beff
        int idx = bid * 256 + tid;
        if (idx < 2560) {
            float v;
            if (idx < 512)       v = bq[idx];
            else if (idx < 1024) v = bk[idx - 512];
            else if (idx < 1536) v = bv[idx - 1024];
            else                 v = btc[idx - 1536];
            bcat1[idx] = v;
        } else if (idx < 3072) {
            int c = idx - 2560;
            float w0, w1, w2; softmax3(scale_w, w0, w1, w2);
            beff[c] = w0 * cb1[c] + w1 * cb2[c] + w2 * cb3[c];
        }
        return;
    }
    bid -= 12;
    {                                       // bias_eff[j], one block per j
        int j = bid;                        // 0..511
        float acc = 0.f;
        #pragma unroll
        for (int m = 0; m < 6; ++m) {
            int k = tid + m * 256;
            float bk_ = (k < 512) ? bo[k] : (k < 1024) ? bwl[k - 512] : bfc[k - 1024];
            acc = fmaf(bk_, Wproj[(size_t)k * 512 + j], acc);
        }
        #pragma unroll
        for (int m = 32; m; m >>= 1) acc += __shfl_xor(acc, m);
        __shared__ float wred[4];
        int w = tid >> 6, l = tid & 63;
        if (l == 0) wred[w] = acc;
        __syncthreads();
        if (tid == 0) bias_eff[j] = bproj[j] + wred[0] + wred[1] + wred[2] + wred[3];
    }
}

// ------------------------------------------------------------------
// Dispatch 2: all weight-side + input-side big GEMMs concurrently.
// [0,256)    conv split-K=4 partials
// [256,576)  qkvt = xpad @ WcatT (+bias, +sigmoid acts), fp32 [512][2560]
// [576,640)  WeffO_T  = (Wproj[0:512]^T) @ Wo^T   -> bf16 [512][512]
// [640,704)  WeffWl_T = (Wproj[512:1024]^T) @ Wwl^T -> bf16 [512][512]
// [704,832)  WeffFc_T = (Wproj[1024:1536]^T) @ Wfc^T -> bf16 [512][1024]
// ------------------------------------------------------------------
__global__ __launch_bounds__(256)
void big_gemms(const unsigned short* __restrict__ xpad,
               const unsigned short* __restrict__ WbigT, float* __restrict__ convP,
               const unsigned short* __restrict__ WcatT, const float* __restrict__ bcat1,
               float* __restrict__ qkvt,
               const unsigned short* __restrict__ WprojT,
               const unsigned short* __restrict__ Wo_b, const unsigned short* __restrict__ Wwl_b,
               const unsigned short* __restrict__ Wfc_b,
               unsigned short* __restrict__ WeffO_T, unsigned short* __restrict__ WeffWl_T,
               unsigned short* __restrict__ WeffFc_T)
{
    __shared__ unsigned short As[2][4096], Bs[2][4096];
    int bid = blockIdx.x;
    if (bid < 256) {
        conv_body(xpad, WbigT, convP, (bid >> 3) & 7, bid & 7, bid >> 6, As, Bs);
        return;
    }
    bid -= 256;
    if (bid < 320) {
        int bm = bid / 40, bn = bid % 40;
        int r0 = bm * 64;
        const unsigned short* Axp = xpad + ((size_t)(r0 >> 8) * 264 + (r0 & 255) + 4) * 512;
        gemm_body<1>(Axp, 512, WcatT + (size_t)bn * 64 * 512, 512, bcat1,
                     qkvt, 2560, r0, bn * 64, 8, As, Bs);
        return;
    }
    bid -= 320;
    if (bid < 64) {
        int bm = bid >> 3, bn = bid & 7;
        gemm_body<4>(WprojT + (size_t)bm * 64 * 1536, 1536, Wo_b + (size_t)bn * 64 * 512, 512,
                     nullptr, WeffO_T, 512, bm * 64, bn * 64, 8, As, Bs);
        return;
    }
    bid -= 64;
    if (bid < 64) {
        int bm = bid >> 3, bn = bid & 7;
        gemm_body<4>(WprojT + 512 + (size_t)bm * 64 * 1536, 1536, Wwl_b + (size_t)bn * 64 * 512, 512,
                     nullptr, WeffWl_T, 512, bm * 64, bn * 64, 8, As, Bs);
        return;
    }
    bid -= 64;
    {   // WeffFc_T: M=512, N=1024, K=512
        int bm = bid >> 4, bn = bid & 15;
        gemm_body<4>(WprojT + 1024 + (size_t)bm * 64 * 1536, 1536, Wfc_b + (size_t)bn * 64 * 512, 512,
                     nullptr, WeffFc_T, 1024, bm * 64, bn * 64, 8, As, Bs);
    }
}

// ------------------------------------------------------------------
// Dispatch 3: branch nonlinears.
// [0,1024)     attn: block = (bi, half), 256 thr = 256 channels
// [1024,2048)  phase: block = (b,c), 256 thr = S
// [2048,3072)  conv split-K reduce -> bf16 convout
// ------------------------------------------------------------------
__global__ __launch_bounds__(256)
void branches(const float* __restrict__ qkvt, const float* __restrict__ phase_shifts,
              const float* __restrict__ convP, const float* __restrict__ beff,
              unsigned short* __restrict__ ctx_b, unsigned short* __restrict__ nc_b,
              unsigned short* __restrict__ convout)
{
    int bid = blockIdx.x, tid = threadIdx.x;
    if (bid < 1024) {                       // wave attention
        const int bi = bid >> 1;
        const int b = bi >> 8, i = bi & 255;
        const int c = ((bid & 1) << 8) + tid;
        const float* qrow = qkvt + (size_t)bi * 2560;
        const float om = qrow[c];
        const float am = qrow[512 + c] * INV_SQRT_D;
        const float ph = tanhf(qrow[1024 + c]) * PI_F;
        const float* vb = qkvt + (size_t)(b * 256) * 2560 + 1024 + c;
        float se = 0.f, sev = 0.f;
        for (int j = 0; j < 256; ++j) {
            float ang = fmaf(om, (float)(i - j), ph);
            float e = __expf(am * __cosf(ang));
            se += e;
            sev = fmaf(e, vb[(size_t)j * 2560], sev);
        }
        ctx_b[(size_t)bi * 512 + c] = f2bf(sev / se);
        return;
    }
    bid -= 1024;
    if (bid < 1024) {                       // phase branch
        const int b = bid >> 9, c = bid & 511;
        const int s = tid;
        const float* row = qkvt + (size_t)(b * 256 + s) * 2560 + 1536;
        float re = row[c], im = row[c + 512];
        float p = atan2f(im, re);
        float mag = sqrtf(fmaf(re, re, fmaf(im, im, 1e-5f)));
        float sp, cp; sincosf(p, &sp, &cp);
        float cs = cp, sn = sp;
        #pragma unroll
        for (int m = 32; m; m >>= 1) { cs += __shfl_xor(cs, m); sn += __shfl_xor(sn, m); }
        __shared__ float wred[8];
        int w = s >> 6, l = s & 63;
        if (l == 0) { wred[w] = cs; wred[4 + w] = sn; }
        __syncthreads();
        float mcv = (wred[0] + wred[1] + wred[2] + wred[3]) * (1.f / 256.f);
        float msv = (wred[4] + wred[5] + wred[6] + wred[7]) * (1.f / 256.f);
        float psh = phase_shifts[c];
        float s2_, c2_; sincosf(p + psh, &s2_, &c2_);
        float mixed = c2_ * mcv + s2_ * msv;
        float np_ = fmaf(0.1f, mixed, p);
        float snn, cnn; sincosf(np_, &snn, &cnn);
        size_t o = (size_t)(b * 256 + s) * 1024 + c;
        nc_b[o]       = f2bf(mag * cnn);
        nc_b[o + 512] = f2bf(mag * snn);
        return;
    }
    bid -= 1024;
    {                                       // conv reduce
        int idx = bid * 256 + tid;
        int c = idx & 511;
        float v = beff[c] + convP[idx] + convP[idx + 262144] + convP[idx + 524288] + convP[idx + 786432];
        convout[idx] = f2bf(v);
    }
}

// ------------------------------------------------------------------
// Dispatch 4: branch-output GEMMs against pre-multiplied weights,
// fp32 partials P[z] (z = 0:ctx@WeffO, 1:conv@WeffWl, 2:nc@WeffFc).
// ------------------------------------------------------------------
__global__ __launch_bounds__(256)
void mid_gemms(const unsigned short* __restrict__ ctx_b, const unsigned short* __restrict__ convout,
               const unsigned short* __restrict__ nc_b,
               const unsigned short* __restrict__ WeffO_T, const unsigned short* __restrict__ WeffWl_T,
               const unsigned short* __restrict__ WeffFc_T,
               float* __restrict__ P)
{
    __shared__ unsigned short As[2][4096], Bs[2][4096];
    int bid = blockIdx.x;
    int z = bid >> 6, bm = (bid >> 3) & 7, bn = bid & 7;
    if (z == 0)
        gemm_body<3>(ctx_b + (size_t)bm * 64 * 512, 512, WeffO_T + (size_t)bn * 64 * 512, 512,
                     nullptr, P, 512, bm * 64, bn * 64, 8, As, Bs);
    else if (z == 1)
        gemm_body<3>(convout + (size_t)bm * 64 * 512, 512, WeffWl_T + (size_t)bn * 64 * 512, 512,
                     nullptr, P + 262144, 512, bm * 64, bn * 64, 8, As, Bs);
    else
        gemm_body<3>(nc_b + (size_t)bm * 64 * 1024, 1024, WeffFc_T + (size_t)bn * 64 * 1024, 1024,
                     nullptr, P + 524288, 512, bm * 64, bn * 64, 16, As, Bs);
}

// ------------------------------------------------------------------
// Dispatch 5: sum partials + bias_eff + residual + LayerNorm -> out
// ------------------------------------------------------------------
__global__ __launch_bounds__(256)
void final_ln(const float* __restrict__ x, const float* __restrict__ P,
              const float* __restrict__ bias_eff,
              const float* __restrict__ g, const float* __restrict__ bta,
              float* __restrict__ out)
{
    int r = blockIdx.x, t = threadIdx.x;
    size_t o0 = (size_t)r * 512 + t, o1 = o0 + 256;
    float c0 = bias_eff[t]       + P[o0] + P[o0 + 262144] + P[o0 + 524288];
    float c1 = bias_eff[t + 256] + P[o1] + P[o1 + 262144] + P[o1 + 524288];
    float v0 = x[o0] + c0, v1 = x[o1] + c1;
    float sum = v0 + v1;
    #pragma unroll
    for (int m = 32; m; m >>= 1) sum += __shfl_xor(sum, m);
    __shared__ float wred[8];
    int w = t >> 6, l = t & 63;
    if (l == 0) wred[w] = sum;
    __syncthreads();
    float mu = (wred[0] + wred[1] + wred[2] + wred[3]) * (1.f / 512.f);
    float d0 = v0 - mu, d1 = v1 - mu;
    float s2 = d0 * d0 + d1 * d1;
    #pragma unroll
    for (int m = 32; m; m >>= 1) s2 += __shfl_xor(s2, m);
    if (l == 0) wred[4 + w] = s2;
    __syncthreads();
    float inv = rsqrtf((wred[4] + wred[5] + wred[6] + wred[7]) * (1.f / 512.f) + 1e-5f);
    out[o0] = d0 * inv * g[t]       + bta[t];
    out[o1] = d1 * inv * g[t + 256] + bta[t + 256];
}

// ------------------------------------------------------------------
extern "C" void kernel_launch(void* const* d_in, const int* in_sizes, int n_in,
                              void* d_out, int out_size, void* d_ws, size_t ws_size,
                              hipStream_t stream)
{
    const float* x   = (const float*)d_in[0];
    const float* Wq  = (const float*)d_in[1];
    const float* bq  = (const float*)d_in[2];
    const float* Wk  = (const float*)d_in[3];
    const float* bk  = (const float*)d_in[4];
    const float* Wv  = (const float*)d_in[5];
    const float* bv  = (const float*)d_in[6];
    const float* Wo  = (const float*)d_in[7];
    const float* bo  = (const float*)d_in[8];
    const float* cw1 = (const float*)d_in[9];
    const float* cb1 = (const float*)d_in[10];
    const float* cw2 = (const float*)d_in[11];
    const float* cb2 = (const float*)d_in[12];
    const float* cw3 = (const float*)d_in[13];
    const float* cb3 = (const float*)d_in[14];
    const float* scale_w = (const float*)d_in[15];
    const float* Wwl = (const float*)d_in[16];
    const float* bwl = (const float*)d_in[17];
    const float* Wtc = (const float*)d_in[18];
    const float* btc = (const float*)d_in[19];
    const float* Wfc = (const float*)d_in[20];
    const float* bfc = (const float*)d_in[21];
    const float* phase_shifts = (const float*)d_in[22];
    const float* Wproj = (const float*)d_in[23];
    const float* bproj = (const float*)d_in[24];
    const float* ln_g = (const float*)d_in[25];
    const float* ln_b = (const float*)d_in[26];
    float* out = (float*)d_out;

    // ---- workspace layout ----
    float* wsf      = (float*)d_ws;
    float* qkvt     = wsf;                      // 1,310,720 f
    float* convP    = qkvt + 1310720;           // 1,048,576 f (4 x 512x512)
    float* P        = convP + 1048576;          //   786,432 f (3 x 512x512)
    float* bcat1    = P + 786432;               //     2,560 f
    float* beff     = bcat1 + 2560;             //       512 f
    float* bias_eff = beff + 512;               //       512 f
    unsigned short* u = (unsigned short*)(bias_eff + 512);
    unsigned short* xpad     = u;                    // 270,336
    unsigned short* WcatT    = xpad + 270336;        // 1,310,720
    unsigned short* WbigT    = WcatT + 1310720;      // 2,359,296
    unsigned short* WprojT   = WbigT + 2359296;      // 786,432
    unsigned short* Wo_b     = WprojT + 786432;      // 262,144
    unsigned short* Wwl_b    = Wo_b + 262144;        // 262,144
    unsigned short* Wfc_b    = Wwl_b + 262144;       // 524,288
    unsigned short* WeffO_T  = Wfc_b + 524288;       // 262,144
    unsigned short* WeffWl_T = WeffO_T + 262144;     // 262,144
    unsigned short* WeffFc_T = WeffWl_T + 262144;    // 524,288
    unsigned short* convout  = WeffFc_T + 524288;    // 262,144
    unsigned short* ctx_b    = convout + 262144;     // 262,144
    unsigned short* nc_b     = ctx_b + 262144;       // 524,288

    prep_all<<<6164, 256, 0, stream>>>(x, Wq, Wk, Wv, Wtc, Wo, Wwl, Wfc, Wproj,
                                       cw1, cw2, cw3, scale_w,
                                       bq, bk, bv, btc, cb1, cb2, cb3,
                                       bo, bwl, bfc, bproj,
                                       xpad, WcatT, WbigT, WprojT,
                                       Wo_b, Wwl_b, Wfc_b,
                                       bcat1, beff, bias_eff);

    big_gemms<<<832, 256, 0, stream>>>(xpad, WbigT, convP, WcatT, bcat1, qkvt,
                                       WprojT, Wo_b, Wwl_b, Wfc_b,
                                       WeffO_T, WeffWl_T, WeffFc_T);

    branches<<<3072, 256, 0, stream>>>(qkvt, phase_shifts, convP, beff,
                                       ctx_b, nc_b, convout);

    mid_gemms<<<192, 256, 0, stream>>>(ctx_b, convout, nc_b,
                                       WeffO_T, WeffWl_T, WeffFc_T, P);

    final_ln<<<512, 256, 0, stream>>>(x, P, bias_eff, ln_g, ln_b, out);
}